// Round 12
// baseline (648.899 us; speedup 1.0000x reference)
//
#include <hip/hip_runtime.h>
#include <cstdint>
#include <cstddef>

#define THREADS 256

typedef __attribute__((ext_vector_type(8))) short bf16x8;
typedef __attribute__((ext_vector_type(4))) float f32x4;
typedef __attribute__((ext_vector_type(2))) float f32x2;

// ---------------------------------------------------------------------------
// JAX threefry2x32 (Random123, 20 rounds) — used for the dropout masks.
// jax_threefry_partitionable=True semantics (verified R1: absmax 0.0156):
// split keys = tf(key,(0,j)); bits[i] = o0^o1 of tf(key,(0,i)).
// ---------------------------------------------------------------------------
__host__ __device__ __forceinline__ void tf2x32(unsigned k0, unsigned k1,
                                                unsigned x0, unsigned x1,
                                                unsigned* o0, unsigned* o1) {
  unsigned ks2 = k0 ^ k1 ^ 0x1BD11BDAu;
  x0 += k0; x1 += k1;
#define TFR(r) { x0 += x1; x1 = (x1 << (r)) | (x1 >> (32 - (r))); x1 ^= x0; }
  TFR(13) TFR(15) TFR(26) TFR(6)   x0 += k1;  x1 += ks2 + 1u;
  TFR(17) TFR(29) TFR(16) TFR(24)  x0 += ks2; x1 += k0 + 2u;
  TFR(13) TFR(15) TFR(26) TFR(6)   x0 += k0;  x1 += k1 + 3u;
  TFR(17) TFR(29) TFR(16) TFR(24)  x0 += k1;  x1 += ks2 + 4u;
  TFR(13) TFR(15) TFR(26) TFR(6)   x0 += ks2; x1 += k0 + 5u;
#undef TFR
  *o0 = x0; *o1 = x1;
}

// fp32 -> bf16 RNE (matches XLA convert); bf16(hi ushort) -> fp32.
__device__ __forceinline__ unsigned f2bf(float f) {
  unsigned b = __float_as_uint(f);
  return (b + 0x7fffu + ((b >> 16) & 1u)) >> 16;
}
__device__ __forceinline__ float bf2f(unsigned hi) {
  return __uint_as_float(hi << 16);
}

// fp32 -> fp8 e4m3 (OCP) via HW cvt (RNE+sat); returns the byte.
__device__ __forceinline__ unsigned char f2fp8(float f) {
  return (unsigned char)(__builtin_amdgcn_cvt_pk_fp8_f32(f, f, 0, false) & 0xff);
}

// Fused BN-affine + ReLU + dropout on 8 consecutive elements of one row,
// using a PRECOMPUTED per-row bitmask (e = even-col bits, o = odd-col bits,
// bit p ↔ cols col0+2p / col0+2p+1). R7: threefry/BN-coef math inside the
// GEMM cost a VGPR occupancy cliff; masks now come from the aggregates.
__device__ __forceinline__ void bn_mask8(float* v, const float* __restrict__ scsh,
                                         int col0, unsigned e, unsigned o) {
  float sc[8], sh[8];
  *(float4*)&sc[0] = *(const float4*)(scsh + col0);
  *(float4*)&sc[4] = *(const float4*)(scsh + col0 + 4);
  *(float4*)&sh[0] = *(const float4*)(scsh + 128 + col0);
  *(float4*)&sh[4] = *(const float4*)(scsh + 128 + col0 + 4);
#pragma unroll
  for (int p = 0; p < 4; ++p) {
    float t0 = fmaxf(v[2 * p] * sc[2 * p] + sh[2 * p], 0.f);
    float t1 = fmaxf(v[2 * p + 1] * sc[2 * p + 1] + sh[2 * p + 1], 0.f);
    v[2 * p] = ((e >> p) & 1u) ? 2.f * t0 : 0.f;
    v[2 * p + 1] = ((o >> p) & 1u) ? 2.f * t1 : 0.f;
  }
}

// ---------------------------------------------------------------------------
// CSR build. Monotone starts (3-kernel scan) + XCD-range-partitioned fill
// @2048 blocks. R11 post-mortem: nontemporal edge reads regressed AGAIN
// (72.6→79 µs at full occupancy; R5+R11 = two controlled data points) —
// the latency cost beats the eviction saving. PLAIN loads, permanently.
// ---------------------------------------------------------------------------
__global__ __launch_bounds__(THREADS) void compute_deg(const int* __restrict__ dst,
                                                       int* __restrict__ deg, int E) {
  int e = blockIdx.x * THREADS + threadIdx.x;
  if (e < E) atomicAdd(&deg[dst[e]], 1);
}

__global__ __launch_bounds__(THREADS) void scan1_local(const int* __restrict__ deg,
                                                       int* __restrict__ start,
                                                       int* __restrict__ blksum, int n) {
  __shared__ int sdata[THREADS];
  int i = blockIdx.x * THREADS + threadIdx.x;
  int d = (i < n) ? deg[i] : 0;
  sdata[threadIdx.x] = d;
  __syncthreads();
  for (int off = 1; off < THREADS; off <<= 1) {
    int v = (threadIdx.x >= off) ? sdata[threadIdx.x - off] : 0;
    __syncthreads();
    sdata[threadIdx.x] += v;
    __syncthreads();
  }
  if (i < n) start[i] = sdata[threadIdx.x] - d;  // local exclusive
  if (threadIdx.x == THREADS - 1) blksum[blockIdx.x] = sdata[THREADS - 1];
}

__global__ __launch_bounds__(512) void scan2_blocks(const int* __restrict__ blksum,
                                                    int* __restrict__ blkbase, int nb) {
  __shared__ int sdata[512];
  int t = threadIdx.x;
  int v = (t < nb) ? blksum[t] : 0;
  sdata[t] = v;
  __syncthreads();
  for (int off = 1; off < 512; off <<= 1) {
    int u = (t >= off) ? sdata[t - off] : 0;
    __syncthreads();
    sdata[t] += u;
    __syncthreads();
  }
  if (t < nb) blkbase[t] = sdata[t] - v;  // exclusive
}

__global__ __launch_bounds__(THREADS) void scan3_add(int* __restrict__ start,
                                                     const int* __restrict__ blkbase,
                                                     int n) {
  int i = blockIdx.x * THREADS + threadIdx.x;
  if (i < n) start[i] += blkbase[blockIdx.x];
}

__global__ __launch_bounds__(THREADS) void fill_csr_xcd(const int* __restrict__ src,
                                                        const int* __restrict__ dst,
                                                        const int* __restrict__ start,
                                                        int* __restrict__ fill,
                                                        int* __restrict__ colbuf,
                                                        int E, int rngw) {
  int g = blockIdx.x & 7;
  int chunk = blockIdx.x >> 3;
  int nchunk = gridDim.x >> 3;
  int lo = g * rngw, hi = lo + rngw;
  int stride = nchunk * THREADS;
  for (int e = chunk * THREADS + threadIdx.x; e < E; e += stride) {
    int d = dst[e];
    if (d >= lo && d < hi) {
      int p = atomicAdd(&fill[d], 1);
      colbuf[start[d] + p] = src[e];
    }
  }
}

// ---------------------------------------------------------------------------
// Pack [Wl | Wr] into MFMA B-fragment order (uint4 per (nt,kc,quad,n)).
// ---------------------------------------------------------------------------
__global__ __launch_bounds__(THREADS) void pack_weights(const float* __restrict__ Wl,
                                                        const float* __restrict__ Wr,
                                                        uint4* __restrict__ Wp) {
  int idx = blockIdx.x * THREADS + threadIdx.x;   // 0..4095
  int n = idx & 15, quad = (idx >> 4) & 3, kc = (idx >> 6) & 3, nt = idx >> 8;
  const float* W = (nt < 8) ? Wl : Wr;
  int col = ((nt & 7) * 16) + n;
  int k0 = kc * 32 + quad * 8;
  unsigned u[4];
#pragma unroll
  for (int p = 0; p < 4; ++p) {
    unsigned lo = f2bf(W[(size_t)(k0 + 2 * p) * 128 + col]);
    unsigned hi = f2bf(W[(size_t)(k0 + 2 * p + 1) * 128 + col]);
    u[p] = lo | (hi << 16);
  }
  Wp[idx] = make_uint4(u[0], u[1], u[2], u[3]);
}

// ---------------------------------------------------------------------------
// Fused dual GEMM via MFMA bf16: Cl = fp8(A'@Wl), Cr = bf16(A'@Wr + bias),
// A' = FUSE ? mask*2*relu(scsh-affine(A)) : A. R12: the whole h-state is now
// BF16 (the next GEMM converts A to bf16 anyway, so fp32 h bought nothing) —
// halves gemm A-read, Cr-write, aggregate rmw, and bn_stats traffic.
// ABF16 selects A dtype (layer 1 reads fp32 x). Cl stays FP8 e4m3 (R10).
// Two-pass accumulator keeps VGPR below the 5-waves/SIMD cliff (R7/R8).
// In-place-safe on Cr==A. A-frag: A[m=lane&15][k=quad*8+j]; C/D: col=lane&15,
// row=quad*4+reg.
// ---------------------------------------------------------------------------
template <int FUSE, int ABF16>
__global__ __launch_bounds__(THREADS) void gemm_dual_mfma(
    const void* Av, const uint4* __restrict__ Wp, const float* __restrict__ bias,
    const float* __restrict__ scsh, const unsigned long long* __restrict__ mask,
    unsigned char* __restrict__ Cl, unsigned short* __restrict__ Cr, int M) {
  int t = threadIdx.x;
  int wv = t >> 6;
  int lane = t & 63;
  int m16 = lane & 15;
  int quad = lane >> 4;
  int arow = blockIdx.x * 64 + wv * 16 + m16;     // A row this lane feeds
  bool avalid = arow < M;

  union U8 { uint4 u; bf16x8 v; };

  unsigned long long m0 = 0, m1 = 0;
  if (FUSE && avalid) {
    m0 = mask[2 * (size_t)arow];
    m1 = mask[2 * (size_t)arow + 1];
  }

  bf16x8 af[4];
#pragma unroll
  for (int kc = 0; kc < 4; ++kc) {
    float v[8] = {0.f, 0.f, 0.f, 0.f, 0.f, 0.f, 0.f, 0.f};
    if (avalid) {
      if (ABF16) {
        const unsigned short* ap =
            (const unsigned short*)Av + (size_t)arow * 128 + quad * 8;
        uint4 ua = *(const uint4*)(ap + kc * 32);
        v[0] = bf2f(ua.x & 0xffffu); v[1] = bf2f(ua.x >> 16);
        v[2] = bf2f(ua.y & 0xffffu); v[3] = bf2f(ua.y >> 16);
        v[4] = bf2f(ua.z & 0xffffu); v[5] = bf2f(ua.z >> 16);
        v[6] = bf2f(ua.w & 0xffffu); v[7] = bf2f(ua.w >> 16);
      } else {
        const float* ap = (const float*)Av + (size_t)arow * 128 + quad * 8;
        *(float4*)&v[0] = *(const float4*)(ap + kc * 32);
        *(float4*)&v[4] = *(const float4*)(ap + kc * 32 + 4);
      }
    }
    if (FUSE) {
      int col0 = kc * 32 + quad * 8;
      int shift = (col0 >> 1);                    // = kc*16 + quad*4
      unsigned e = (unsigned)(m0 >> shift) & 0xFu;
      unsigned o = (unsigned)(m1 >> shift) & 0xFu;
      bn_mask8(v, scsh, col0, e, o);
    }
    U8 u;
    u.u.x = f2bf(v[0]) | (f2bf(v[1]) << 16);
    u.u.y = f2bf(v[2]) | (f2bf(v[3]) << 16);
    u.u.z = f2bf(v[4]) | (f2bf(v[5]) << 16);
    u.u.w = f2bf(v[6]) | (f2bf(v[7]) << 16);
    af[kc] = u.v;
  }

  int orow0 = blockIdx.x * 64 + wv * 16 + quad * 4;
  const uint4* wp = Wp + m16;   // + ((nt*4+kc)*4+quad)*16

  // ---- pass 1: nt 0..7 → Cl (fp8 e4m3) ----
  {
    f32x4 acc[8];
#pragma unroll
    for (int i = 0; i < 8; ++i) acc[i] = (f32x4){0.f, 0.f, 0.f, 0.f};
#pragma unroll
    for (int nt = 0; nt < 8; ++nt) {
#pragma unroll
      for (int kc = 0; kc < 4; ++kc) {
        U8 b;
        b.u = wp[((nt * 4 + kc) * 4 + quad) * 16];
        acc[nt] = __builtin_amdgcn_mfma_f32_16x16x32_bf16(af[kc], b.v, acc[nt], 0, 0, 0);
      }
    }
#pragma unroll
    for (int nt = 0; nt < 8; ++nt) {
      int col = nt * 16 + m16;
#pragma unroll
      for (int r = 0; r < 4; ++r) {
        int row = orow0 + r;
        if (row < M) Cl[(size_t)row * 128 + col] = f2fp8(acc[nt][r]);
      }
    }
  }

  // ---- pass 2: nt 8..15 → Cr (bf16 + bias) ----
  {
    f32x4 acc[8];
#pragma unroll
    for (int i = 0; i < 8; ++i) acc[i] = (f32x4){0.f, 0.f, 0.f, 0.f};
#pragma unroll
    for (int nt = 0; nt < 8; ++nt) {
#pragma unroll
      for (int kc = 0; kc < 4; ++kc) {
        U8 b;
        b.u = wp[(((nt + 8) * 4 + kc) * 4 + quad) * 16];
        acc[nt] = __builtin_amdgcn_mfma_f32_16x16x32_bf16(af[kc], b.v, acc[nt], 0, 0, 0);
      }
    }
#pragma unroll
    for (int nt = 0; nt < 8; ++nt) {
      int col = nt * 16 + m16;
      float bb = bias[col];
#pragma unroll
      for (int r = 0; r < 4; ++r) {
        int row = orow0 + r;
        if (row < M)
          Cr[(size_t)row * 128 + col] = (unsigned short)f2bf(acc[nt][r] + bb);
      }
    }
  }
}

// ---------------------------------------------------------------------------
// Fused layer-3 projections: Cl = bf16(A'@Wl), Cr = A'@Wr + br (fp32 out),
// A' = mask2*2*relu(scsh2-affine(A)), A in bf16. Reads A ONCE.
// ---------------------------------------------------------------------------
__global__ __launch_bounds__(THREADS) void gemm16_dual(const unsigned short* __restrict__ A,
                                                       const float* __restrict__ Wl,
                                                       const float* __restrict__ Wr,
                                                       const float* __restrict__ br,
                                                       const float* __restrict__ scsh,
                                                       const unsigned long long* __restrict__ mask,
                                                       unsigned short* __restrict__ Cl,
                                                       float* __restrict__ Cr, int M) {
  __shared__ __align__(16) float Wls[128][16];  // [k][col]
  __shared__ __align__(16) float Wrs[128][16];
  __shared__ __align__(16) float As[16][130];   // [row][k], +2 pad
  int t = threadIdx.x;
#pragma unroll
  for (int i = 0; i < 2; ++i) {
    int lin = (t + i * THREADS) << 2;           // float4 id → float offset
    *(float4*)&Wls[0][lin & 2047] = *(const float4*)(Wl + lin);
    *(float4*)&Wrs[0][lin & 2047] = *(const float4*)(Wr + lin);
  }
  int row0 = blockIdx.x * 16;
  int r = t >> 4;     // 0..15 local row
  int c = t & 15;     // col / chunk id
  {
    int grow = row0 + r;
    float v[8] = {0.f, 0.f, 0.f, 0.f, 0.f, 0.f, 0.f, 0.f};
    if (grow < M) {
      uint4 ua = *(const uint4*)(A + (size_t)grow * 128 + c * 8);
      v[0] = bf2f(ua.x & 0xffffu); v[1] = bf2f(ua.x >> 16);
      v[2] = bf2f(ua.y & 0xffffu); v[3] = bf2f(ua.y >> 16);
      v[4] = bf2f(ua.z & 0xffffu); v[5] = bf2f(ua.z >> 16);
      v[6] = bf2f(ua.w & 0xffffu); v[7] = bf2f(ua.w >> 16);
      unsigned long long m0 = mask[2 * (size_t)grow];
      unsigned long long m1 = mask[2 * (size_t)grow + 1];
      int shift = c * 4;                         // (c*8)/2
      unsigned e = (unsigned)(m0 >> shift) & 0xFu;
      unsigned o = (unsigned)(m1 >> shift) & 0xFu;
      bn_mask8(v, scsh, c * 8, e, o);
    }
    *(float4*)&As[r][c * 8] = *(float4*)&v[0];
    *(float4*)&As[r][c * 8 + 4] = *(float4*)&v[4];
  }
  __syncthreads();
  float accl = 0.f, accr = 0.f;
#pragma unroll 4
  for (int k = 0; k < 128; ++k) {
    float a = As[r][k];                          // broadcast across 16 lanes
    accl += a * Wls[k][c];
    accr += a * Wrs[k][c];
  }
  int grow = row0 + r;
  if (grow < M) {
    Cl[(size_t)grow * 16 + c] = (unsigned short)f2bf(accl);
    Cr[(size_t)grow * 16 + c] = accr + br[c];
  }
}

// ---------------------------------------------------------------------------
// Z[n] (bf16) += agg(Yfp8)[n] / max(deg,1): one wave per node; two 32-lane
// halves process two edges per instruction; lane covers 4 fp8 cols. fp8 rows
// = 2 lines/edge (R10 win); Z is now bf16 (uint2 rmw instead of float4).
// HW pk decode fp8→f32. Mask ballot stream unchanged (bit-identical dropout).
// ---------------------------------------------------------------------------
__global__ __launch_bounds__(THREADS) void aggregate128_fp8(
    const unsigned char* __restrict__ Y, unsigned short* __restrict__ Z,
    const int* __restrict__ colbuf, const int* __restrict__ start,
    const int* __restrict__ deg, unsigned long long* __restrict__ mask,
    unsigned mk0, unsigned mk1, int nnodes) {
  int w = (blockIdx.x * THREADS + threadIdx.x) >> 6;  // node = global wave id
  int lane = threadIdx.x & 63;
  if (w >= nnodes) return;
  // dropout mask bits for this node's row (index-only; overlaps the gathers)
  unsigned a0, a1, b0, b1;
  unsigned ib = (unsigned)w * 128u + (unsigned)(lane << 1);
  tf2x32(mk0, mk1, 0u, ib, &a0, &a1);
  tf2x32(mk0, mk1, 0u, ib + 1u, &b0, &b1);
  bool kp0 = ((a0 ^ a1) >> 31) == 0u;
  bool kp1 = ((b0 ^ b1) >> 31) == 0u;

  int half = lane >> 5;         // 0: even edge of pair, 1: odd edge
  int l32 = lane & 31;
  const int* cb = colbuf + start[w];
  int dg = deg[w];
  const unsigned char* yp = Y + (l32 << 2);      // 4 fp8 cols per lane
  float a0f = 0.f, a1f = 0.f, a2f = 0.f, a3f = 0.f;
  int i = 0;
#define ACC(u) { \
    f32x2 lo = __builtin_amdgcn_cvt_pk_f32_fp8((int)(u), false); \
    f32x2 hi = __builtin_amdgcn_cvt_pk_f32_fp8((int)(u), true);  \
    a0f += lo.x; a1f += lo.y; a2f += hi.x; a3f += hi.y; }
  for (; i + 8 <= dg; i += 8) {                  // 8 edges = 4 uint loads/lane
    int e0 = cb[i + half], e1 = cb[i + 2 + half];
    int e2 = cb[i + 4 + half], e3 = cb[i + 6 + half];
    unsigned u0 = *(const unsigned*)(yp + (size_t)e0 * 128);
    unsigned u1 = *(const unsigned*)(yp + (size_t)e1 * 128);
    unsigned u2 = *(const unsigned*)(yp + (size_t)e2 * 128);
    unsigned u3 = *(const unsigned*)(yp + (size_t)e3 * 128);
    ACC(u0) ACC(u1) ACC(u2) ACC(u3)
  }
  for (; i + 2 <= dg; i += 2) {
    int e0 = cb[i + half];
    unsigned u0 = *(const unsigned*)(yp + (size_t)e0 * 128);
    ACC(u0)
  }
  if (i < dg) {                                  // odd tail: half 0 only
    int e0 = cb[i];
    unsigned u0 = *(const unsigned*)(yp + (size_t)e0 * 128);
    if (half == 0) { ACC(u0) }
  }
#undef ACC
  // combine halves: lanes 0..31 += lanes 32..63 (same cols)
  a0f += __shfl(a0f, lane + 32);
  a1f += __shfl(a1f, lane + 32);
  a2f += __shfl(a2f, lane + 32);
  a3f += __shfl(a3f, lane + 32);

  unsigned long long bm0 = __ballot(kp0);
  unsigned long long bm1 = __ballot(kp1);
  if (lane == 0) {
    mask[2 * (size_t)w] = bm0;
    mask[2 * (size_t)w + 1] = bm1;
  }
  if (half == 0) {
    float sc = 1.0f / fmaxf((float)dg, 1.0f);
    unsigned short* zp = Z + (size_t)w * 128 + (l32 << 2);
    uint2 z = *(const uint2*)zp;
    float z0 = bf2f(z.x & 0xffffu) + a0f * sc;
    float z1 = bf2f(z.x >> 16) + a1f * sc;
    float z2 = bf2f(z.y & 0xffffu) + a2f * sc;
    float z3 = bf2f(z.y >> 16) + a3f * sc;
    uint2 o;
    o.x = f2bf(z0) | (f2bf(z1) << 16);
    o.y = f2bf(z2) | (f2bf(z3) << 16);
    *(uint2*)zp = o;
  }
}

// Out[n] += agg(Y16bf16)[n] / max(deg,1): 8 threads/node, ×8 edge unroll.
__global__ __launch_bounds__(THREADS) void aggregate16_bf16(
    const unsigned short* __restrict__ Y, float* __restrict__ Out,
    const int* __restrict__ colbuf, const int* __restrict__ start,
    const int* __restrict__ deg, int nnodes) {
  int gid = blockIdx.x * THREADS + threadIdx.x;
  int n = gid >> 3;
  int cp = gid & 7;             // col pair: cols 2cp, 2cp+1
  if (n >= nnodes) return;
  const int* cb = colbuf + start[n];
  int dg = deg[n];
  const unsigned short* yp = Y + (cp << 1);
  float ax = 0.f, ay = 0.f;
  int i = 0;
  for (; i + 8 <= dg; i += 8) {
    int e[8];
#pragma unroll
    for (int j = 0; j < 8; ++j) e[j] = cb[i + j];
    unsigned u[8];
#pragma unroll
    for (int j = 0; j < 8; ++j) u[j] = *(const unsigned*)(yp + (size_t)e[j] * 16);
#pragma unroll
    for (int j = 0; j < 8; ++j) {
      ax += __uint_as_float(u[j] << 16);
      ay += __uint_as_float(u[j] & 0xffff0000u);
    }
  }
  for (; i < dg; ++i) {
    unsigned u = *(const unsigned*)(yp + (size_t)cb[i] * 16);
    ax += __uint_as_float(u << 16);
    ay += __uint_as_float(u & 0xffff0000u);
  }
  float sc = 1.0f / fmaxf((float)dg, 1.0f);
  size_t off = (size_t)n * 16 + (cp << 1);
  float2 o = *(const float2*)(Out + off);
  o.x += ax * sc;
  o.y += ay * sc;
  *(float2*)(Out + off) = o;
}

// ---------------------------------------------------------------------------
// BN: column sums/sumsq over the bf16 h-state (uint pair loads), @1024
// blocks (R11 grid fix). Thread t: col pair cp = t&63, row group t>>6.
// ---------------------------------------------------------------------------
__global__ __launch_bounds__(THREADS) void bn_stats_bf16(
    const unsigned short* __restrict__ H, float* __restrict__ sums, int n) {
  int cp = threadIdx.x & 63;    // cols 2cp, 2cp+1
  int grp = threadIdx.x >> 6;   // 0..3
  float s0 = 0.f, q0 = 0.f, s1 = 0.f, q1 = 0.f;
  for (int r = blockIdx.x * 4 + grp; r < n; r += gridDim.x * 4) {
    unsigned u = *(const unsigned*)(H + (size_t)r * 128 + (cp << 1));
    float v0 = bf2f(u & 0xffffu);
    float v1 = bf2f(u >> 16);
    s0 += v0; q0 += v0 * v0;
    s1 += v1; q1 += v1 * v1;
  }
  __shared__ float L0[THREADS], L1[THREADS], L2[THREADS], L3[THREADS];
  L0[threadIdx.x] = s0; L1[threadIdx.x] = q0;
  L2[threadIdx.x] = s1; L3[threadIdx.x] = q1;
  __syncthreads();
  if (grp == 0) {
#pragma unroll
    for (int j = 1; j < 4; ++j) {
      s0 += L0[cp + j * 64]; q0 += L1[cp + j * 64];
      s1 += L2[cp + j * 64]; q1 += L3[cp + j * 64];
    }
    atomicAdd(&sums[2 * cp], s0);
    atomicAdd(&sums[2 * cp + 1], s1);
    atomicAdd(&sums[128 + 2 * cp], q0);
    atomicAdd(&sums[128 + 2 * cp + 1], q1);
  }
}

__global__ void bn_finalize(const float* __restrict__ sums,
                            const float* __restrict__ g,
                            const float* __restrict__ be,
                            float* __restrict__ scsh, float n) {
  int c = threadIdx.x;  // 128 threads
  float mu = sums[c] / n;
  float var = sums[128 + c] / n - mu * mu;
  float inv = rsqrtf(var + 1e-5f);
  float sc = g[c] * inv;
  scsh[c] = sc;
  scsh[128 + c] = be[c] - mu * sc;
}

// ---------------------------------------------------------------------------
// Launch: ONE memset; pack weights; CSR; per layer: fused MFMA dual GEMM
// (prev BN via scsh + precomputed mask; Cl fp8, Cr/h-state bf16), fp8
// gather-agg (+ mask gen), bn_stats_bf16, bn_finalize. Layer-3: fused dual
// 16-wide GEMM (bf16 A and Cl) + agg16.
// ---------------------------------------------------------------------------
extern "C" void kernel_launch(void* const* d_in, const int* in_sizes, int n_in,
                              void* d_out, int out_size, void* d_ws, size_t ws_size,
                              hipStream_t stream) {
  const float* x   = (const float*)d_in[0];
  const int* eidx  = (const int*)d_in[1];
  const float* W1l = (const float*)d_in[2];
  const float* W1r = (const float*)d_in[3];
  const float* b1  = (const float*)d_in[4];
  const float* g1  = (const float*)d_in[5];
  const float* be1 = (const float*)d_in[6];
  const float* W2l = (const float*)d_in[7];
  const float* W2r = (const float*)d_in[8];
  const float* b2  = (const float*)d_in[9];
  const float* g2  = (const float*)d_in[10];
  const float* be2 = (const float*)d_in[11];
  const float* W3l = (const float*)d_in[12];
  const float* W3r = (const float*)d_in[13];
  const float* b3  = (const float*)d_in[14];
  float* out = (float*)d_out;

  const int N = in_sizes[0] / 128;
  const int E = in_sizes[1] / 2;
  const int* esrc = eidx;
  const int* edst = eidx + E;

  size_t N128 = (size_t)N * 128;
  // Cleared region first (one memset): sums1(256) sums2(256) ideg(N) ifill(N)
  float* sums1 = (float*)d_ws;
  float* sums2 = sums1 + 256;
  int* ideg    = (int*)(sums2 + 256);
  int* ifill   = ideg + N;
  // Uncleared:
  int* istart  = ifill + N;
  int* iblksum = istart + N;                  // 512
  int* iblkbase = iblksum + 512;              // 512
  float* scsh1 = (float*)(iblkbase + 512);    // 256
  float* scsh2 = scsh1 + 256;                 // 256
  uint4* wp1 = (uint4*)(scsh2 + 256);         // 4096 uint4 each = 64 KB
  uint4* wp2 = wp1 + 4096;
  unsigned long long* mask1 = (unsigned long long*)(wp2 + 4096);  // N×2 u64
  unsigned long long* mask2 = mask1 + 2 * (size_t)N;
  int* icol  = (int*)(mask2 + 2 * (size_t)N);
  unsigned short* buf0h = (unsigned short*)(icol + E);  // fp8/bf16 N×128
  unsigned short* buf1h = buf0h + N128;                 // bf16 h-state N×128
  unsigned char* buf0b = (unsigned char*)buf0h;         // fp8 view (layers 1-2)

  // dropout keys: k1,k2 = split(key(42)) under partitionable threefry
  unsigned k1a, k1b, k2a, k2b;
  tf2x32(0u, 42u, 0u, 0u, &k1a, &k1b);
  tf2x32(0u, 42u, 0u, 1u, &k2a, &k2b);

  hipMemsetAsync(sums1, 0, (512 + 2 * (size_t)N) * 4, stream);

  pack_weights<<<16, THREADS, 0, stream>>>(W1l, W1r, wp1);
  pack_weights<<<16, THREADS, 0, stream>>>(W2l, W2r, wp2);

  int gE = (E + THREADS - 1) / THREADS;
  int gN = (N + THREADS - 1) / THREADS;      // == #scan blocks, must be <=512
  compute_deg<<<gE, THREADS, 0, stream>>>(edst, ideg, E);
  scan1_local<<<gN, THREADS, 0, stream>>>(ideg, istart, iblksum, N);
  scan2_blocks<<<1, 512, 0, stream>>>(iblksum, iblkbase, gN);
  scan3_add<<<gN, THREADS, 0, stream>>>(istart, iblkbase, N);
  int rngw = (N + 7) / 8;
  fill_csr_xcd<<<2048, THREADS, 0, stream>>>(esrc, edst, istart, ifill, icol, E, rngw);

  int gM64 = (N + 63) / 64;
  int gW = (N + 3) / 4;                 // aggregate128: 4 waves/block
  int gA16 = (N * 8 + THREADS - 1) / THREADS;
  float nf = (float)N;

  // ---- Layer 1 (A = fp32 x) ----
  gemm_dual_mfma<0, 0><<<gM64, THREADS, 0, stream>>>(x, wp1, b1, nullptr, nullptr,
                                                     buf0b, buf1h, N);
  aggregate128_fp8<<<gW, THREADS, 0, stream>>>(buf0b, buf1h, icol, istart, ideg,
                                               mask1, k1a, k1b, N);
  bn_stats_bf16<<<1024, THREADS, 0, stream>>>(buf1h, sums1, N);
  bn_finalize<<<1, 128, 0, stream>>>(sums1, g1, be1, scsh1, nf);

  // ---- Layer 2 (A = bf16 h; BN1+drop1 via scsh1+mask1; in-place on buf1h) ----
  gemm_dual_mfma<1, 1><<<gM64, THREADS, 0, stream>>>(buf1h, wp2, b2, scsh1, mask1,
                                                     buf0b, buf1h, N);
  aggregate128_fp8<<<gW, THREADS, 0, stream>>>(buf0b, buf1h, icol, istart, ideg,
                                               mask2, k2a, k2b, N);
  bn_stats_bf16<<<1024, THREADS, 0, stream>>>(buf1h, sums2, N);
  bn_finalize<<<1, 128, 0, stream>>>(sums2, g2, be2, scsh2, nf);

  // ---- Layer 3 (BN2+drop2 via scsh2+mask2 in dual 16-wide GEMM) ----
  gemm16_dual<<<(N + 15) / 16, THREADS, 0, stream>>>(buf1h, W3l, W3r, b3, scsh2,
                                                     mask2, buf0h, out, N);
  aggregate16_bf16<<<gA16, THREADS, 0, stream>>>(buf0h, out, icol, istart, ideg, N);
}

// Round 13
// 613.525 us; speedup vs baseline: 1.0577x; 1.0577x over previous
//
#include <hip/hip_runtime.h>
#include <cstdint>
#include <cstddef>

#define THREADS 256

typedef __attribute__((ext_vector_type(8))) short bf16x8;
typedef __attribute__((ext_vector_type(4))) float f32x4;
typedef __attribute__((ext_vector_type(2))) float f32x2;

// ---------------------------------------------------------------------------
// JAX threefry2x32 (Random123, 20 rounds) — used for the dropout masks.
// jax_threefry_partitionable=True semantics (verified R1: absmax 0.0156):
// split keys = tf(key,(0,j)); bits[i] = o0^o1 of tf(key,(0,i)).
// ---------------------------------------------------------------------------
__host__ __device__ __forceinline__ void tf2x32(unsigned k0, unsigned k1,
                                                unsigned x0, unsigned x1,
                                                unsigned* o0, unsigned* o1) {
  unsigned ks2 = k0 ^ k1 ^ 0x1BD11BDAu;
  x0 += k0; x1 += k1;
#define TFR(r) { x0 += x1; x1 = (x1 << (r)) | (x1 >> (32 - (r))); x1 ^= x0; }
  TFR(13) TFR(15) TFR(26) TFR(6)   x0 += k1;  x1 += ks2 + 1u;
  TFR(17) TFR(29) TFR(16) TFR(24)  x0 += ks2; x1 += k0 + 2u;
  TFR(13) TFR(15) TFR(26) TFR(6)   x0 += k0;  x1 += k1 + 3u;
  TFR(17) TFR(29) TFR(16) TFR(24)  x0 += k1;  x1 += ks2 + 4u;
  TFR(13) TFR(15) TFR(26) TFR(6)   x0 += ks2; x1 += k0 + 5u;
#undef TFR
  *o0 = x0; *o1 = x1;
}

// fp32 -> bf16 with round-to-nearest-even (matches XLA convert semantics).
__device__ __forceinline__ unsigned f2bf(float f) {
  unsigned b = __float_as_uint(f);
  return (b + 0x7fffu + ((b >> 16) & 1u)) >> 16;
}

// fp32 -> fp8 e4m3 (OCP) via HW cvt (RNE+sat); returns the byte.
__device__ __forceinline__ unsigned char f2fp8(float f) {
  return (unsigned char)(__builtin_amdgcn_cvt_pk_fp8_f32(f, f, 0, false) & 0xff);
}

// Fused BN-affine + ReLU + dropout on 8 consecutive elements of one row,
// using a PRECOMPUTED per-row bitmask (e = even-col bits, o = odd-col bits,
// bit p ↔ cols col0+2p / col0+2p+1). R7: threefry/BN-coef math inside the
// GEMM cost a VGPR occupancy cliff; masks now come from the aggregates.
// R12 post-mortem: h-state stays FP32 — bf16 h added unpack VALU to
// issue-bound consumers (aggregate, gemm A-load) and regressed 28 µs.
__device__ __forceinline__ void bn_mask8(float* v, const float* __restrict__ scsh,
                                         int col0, unsigned e, unsigned o) {
  float sc[8], sh[8];
  *(float4*)&sc[0] = *(const float4*)(scsh + col0);
  *(float4*)&sc[4] = *(const float4*)(scsh + col0 + 4);
  *(float4*)&sh[0] = *(const float4*)(scsh + 128 + col0);
  *(float4*)&sh[4] = *(const float4*)(scsh + 128 + col0 + 4);
#pragma unroll
  for (int p = 0; p < 4; ++p) {
    float t0 = fmaxf(v[2 * p] * sc[2 * p] + sh[2 * p], 0.f);
    float t1 = fmaxf(v[2 * p + 1] * sc[2 * p + 1] + sh[2 * p + 1], 0.f);
    v[2 * p] = ((e >> p) & 1u) ? 2.f * t0 : 0.f;
    v[2 * p + 1] = ((o >> p) & 1u) ? 2.f * t1 : 0.f;
  }
}

// ---------------------------------------------------------------------------
// CSR build. Monotone starts (3-kernel scan) + XCD-range-partitioned fill
// @2048 blocks, PLAIN loads (nontemporal regressed in both R5 and R11 —
// theory closed, never again).
// ---------------------------------------------------------------------------
__global__ __launch_bounds__(THREADS) void compute_deg(const int* __restrict__ dst,
                                                       int* __restrict__ deg, int E) {
  int e = blockIdx.x * THREADS + threadIdx.x;
  if (e < E) atomicAdd(&deg[dst[e]], 1);
}

__global__ __launch_bounds__(THREADS) void scan1_local(const int* __restrict__ deg,
                                                       int* __restrict__ start,
                                                       int* __restrict__ blksum, int n) {
  __shared__ int sdata[THREADS];
  int i = blockIdx.x * THREADS + threadIdx.x;
  int d = (i < n) ? deg[i] : 0;
  sdata[threadIdx.x] = d;
  __syncthreads();
  for (int off = 1; off < THREADS; off <<= 1) {
    int v = (threadIdx.x >= off) ? sdata[threadIdx.x - off] : 0;
    __syncthreads();
    sdata[threadIdx.x] += v;
    __syncthreads();
  }
  if (i < n) start[i] = sdata[threadIdx.x] - d;  // local exclusive
  if (threadIdx.x == THREADS - 1) blksum[blockIdx.x] = sdata[THREADS - 1];
}

__global__ __launch_bounds__(512) void scan2_blocks(const int* __restrict__ blksum,
                                                    int* __restrict__ blkbase, int nb) {
  __shared__ int sdata[512];
  int t = threadIdx.x;
  int v = (t < nb) ? blksum[t] : 0;
  sdata[t] = v;
  __syncthreads();
  for (int off = 1; off < 512; off <<= 1) {
    int u = (t >= off) ? sdata[t - off] : 0;
    __syncthreads();
    sdata[t] += u;
    __syncthreads();
  }
  if (t < nb) blkbase[t] = sdata[t] - v;  // exclusive
}

__global__ __launch_bounds__(THREADS) void scan3_add(int* __restrict__ start,
                                                     const int* __restrict__ blkbase,
                                                     int n) {
  int i = blockIdx.x * THREADS + threadIdx.x;
  if (i < n) start[i] += blkbase[blockIdx.x];
}

__global__ __launch_bounds__(THREADS) void fill_csr_xcd(const int* __restrict__ src,
                                                        const int* __restrict__ dst,
                                                        const int* __restrict__ start,
                                                        int* __restrict__ fill,
                                                        int* __restrict__ colbuf,
                                                        int E, int rngw) {
  int g = blockIdx.x & 7;
  int chunk = blockIdx.x >> 3;
  int nchunk = gridDim.x >> 3;
  int lo = g * rngw, hi = lo + rngw;
  int stride = nchunk * THREADS;
  for (int e = chunk * THREADS + threadIdx.x; e < E; e += stride) {
    int d = dst[e];
    if (d >= lo && d < hi) {
      int p = atomicAdd(&fill[d], 1);
      colbuf[start[d] + p] = src[e];
    }
  }
}

// ---------------------------------------------------------------------------
// Pack [Wl | Wr] into MFMA B-fragment order (uint4 per (nt,kc,quad,n)).
// ---------------------------------------------------------------------------
__global__ __launch_bounds__(THREADS) void pack_weights(const float* __restrict__ Wl,
                                                        const float* __restrict__ Wr,
                                                        uint4* __restrict__ Wp) {
  int idx = blockIdx.x * THREADS + threadIdx.x;   // 0..4095
  int n = idx & 15, quad = (idx >> 4) & 3, kc = (idx >> 6) & 3, nt = idx >> 8;
  const float* W = (nt < 8) ? Wl : Wr;
  int col = ((nt & 7) * 16) + n;
  int k0 = kc * 32 + quad * 8;
  unsigned u[4];
#pragma unroll
  for (int p = 0; p < 4; ++p) {
    unsigned lo = f2bf(W[(size_t)(k0 + 2 * p) * 128 + col]);
    unsigned hi = f2bf(W[(size_t)(k0 + 2 * p + 1) * 128 + col]);
    u[p] = lo | (hi << 16);
  }
  Wp[idx] = make_uint4(u[0], u[1], u[2], u[3]);
}

// ---------------------------------------------------------------------------
// Fused dual GEMM via MFMA bf16: Cl = fp8(A'@Wl), Cr = A'@Wr + bias (fp32),
// A' = FUSE ? mask*2*relu(scsh-affine(A)) : A. Cl is FP8 e4m3 (R10: halves
// the aggregate's LLC line-service count; BN renormalizes the noise).
// Two-pass accumulator keeps VGPR below the 5-waves/SIMD cliff (R7/R8).
// In-place-safe on Cr==A.
// A-frag: A[m=lane&15][k=quad*8+j]; C/D: col=lane&15, row=quad*4+reg.
// ---------------------------------------------------------------------------
template <int FUSE>
__global__ __launch_bounds__(THREADS) void gemm_dual_mfma(
    const float* A, const uint4* __restrict__ Wp, const float* __restrict__ bias,
    const float* __restrict__ scsh, const unsigned long long* __restrict__ mask,
    unsigned char* __restrict__ Cl, float* __restrict__ Cr, int M) {
  int t = threadIdx.x;
  int wv = t >> 6;
  int lane = t & 63;
  int m16 = lane & 15;
  int quad = lane >> 4;
  int arow = blockIdx.x * 64 + wv * 16 + m16;     // A row this lane feeds
  bool avalid = arow < M;

  union U8 { uint4 u; bf16x8 v; };

  unsigned long long m0 = 0, m1 = 0;
  if (FUSE && avalid) {
    m0 = mask[2 * (size_t)arow];
    m1 = mask[2 * (size_t)arow + 1];
  }

  bf16x8 af[4];
  const float* ap = A + (size_t)arow * 128 + quad * 8;
#pragma unroll
  for (int kc = 0; kc < 4; ++kc) {
    float v[8] = {0.f, 0.f, 0.f, 0.f, 0.f, 0.f, 0.f, 0.f};
    if (avalid) {
      *(float4*)&v[0] = *(const float4*)(ap + kc * 32);
      *(float4*)&v[4] = *(const float4*)(ap + kc * 32 + 4);
    }
    if (FUSE) {
      int col0 = kc * 32 + quad * 8;
      int shift = (col0 >> 1);                    // = kc*16 + quad*4
      unsigned e = (unsigned)(m0 >> shift) & 0xFu;
      unsigned o = (unsigned)(m1 >> shift) & 0xFu;
      bn_mask8(v, scsh, col0, e, o);
    }
    U8 u;
    u.u.x = f2bf(v[0]) | (f2bf(v[1]) << 16);
    u.u.y = f2bf(v[2]) | (f2bf(v[3]) << 16);
    u.u.z = f2bf(v[4]) | (f2bf(v[5]) << 16);
    u.u.w = f2bf(v[6]) | (f2bf(v[7]) << 16);
    af[kc] = u.v;
  }

  int orow0 = blockIdx.x * 64 + wv * 16 + quad * 4;
  const uint4* wp = Wp + m16;   // + ((nt*4+kc)*4+quad)*16

  // ---- pass 1: nt 0..7 → Cl (fp8 e4m3) ----
  {
    f32x4 acc[8];
#pragma unroll
    for (int i = 0; i < 8; ++i) acc[i] = (f32x4){0.f, 0.f, 0.f, 0.f};
#pragma unroll
    for (int nt = 0; nt < 8; ++nt) {
#pragma unroll
      for (int kc = 0; kc < 4; ++kc) {
        U8 b;
        b.u = wp[((nt * 4 + kc) * 4 + quad) * 16];
        acc[nt] = __builtin_amdgcn_mfma_f32_16x16x32_bf16(af[kc], b.v, acc[nt], 0, 0, 0);
      }
    }
#pragma unroll
    for (int nt = 0; nt < 8; ++nt) {
      int col = nt * 16 + m16;
#pragma unroll
      for (int r = 0; r < 4; ++r) {
        int row = orow0 + r;
        if (row < M) Cl[(size_t)row * 128 + col] = f2fp8(acc[nt][r]);
      }
    }
  }

  // ---- pass 2: nt 8..15 → Cr (fp32 + bias) ----
  {
    f32x4 acc[8];
#pragma unroll
    for (int i = 0; i < 8; ++i) acc[i] = (f32x4){0.f, 0.f, 0.f, 0.f};
#pragma unroll
    for (int nt = 0; nt < 8; ++nt) {
#pragma unroll
      for (int kc = 0; kc < 4; ++kc) {
        U8 b;
        b.u = wp[(((nt + 8) * 4 + kc) * 4 + quad) * 16];
        acc[nt] = __builtin_amdgcn_mfma_f32_16x16x32_bf16(af[kc], b.v, acc[nt], 0, 0, 0);
      }
    }
#pragma unroll
    for (int nt = 0; nt < 8; ++nt) {
      int col = nt * 16 + m16;
      float bb = bias[col];
#pragma unroll
      for (int r = 0; r < 4; ++r) {
        int row = orow0 + r;
        if (row < M) Cr[(size_t)row * 128 + col] = acc[nt][r] + bb;
      }
    }
  }
}

// ---------------------------------------------------------------------------
// Fused layer-3 projections: Cl = bf16(A'@Wl), Cr = A'@Wr + br, where
// A' = mask2*2*relu(scsh2-affine(A)) applied on load. Reads A ONCE.
// Layer-3 Cl stays BF16: its aggregate feeds `out` directly (no BN to absorb
// fp8 noise) and agg16 is cheap anyway.
// ---------------------------------------------------------------------------
__global__ __launch_bounds__(THREADS) void gemm16_dual(const float* __restrict__ A,
                                                       const float* __restrict__ Wl,
                                                       const float* __restrict__ Wr,
                                                       const float* __restrict__ br,
                                                       const float* __restrict__ scsh,
                                                       const unsigned long long* __restrict__ mask,
                                                       unsigned short* __restrict__ Cl,
                                                       float* __restrict__ Cr, int M) {
  __shared__ __align__(16) float Wls[128][16];  // [k][col]
  __shared__ __align__(16) float Wrs[128][16];
  __shared__ __align__(16) float As[16][130];   // [row][k], +2 pad
  int t = threadIdx.x;
#pragma unroll
  for (int i = 0; i < 2; ++i) {
    int lin = (t + i * THREADS) << 2;           // float4 id → float offset
    *(float4*)&Wls[0][lin & 2047] = *(const float4*)(Wl + lin);
    *(float4*)&Wrs[0][lin & 2047] = *(const float4*)(Wr + lin);
  }
  int row0 = blockIdx.x * 16;
  int r = t >> 4;     // 0..15 local row
  int c = t & 15;     // col / chunk id
  {
    int grow = row0 + r;
    float v[8] = {0.f, 0.f, 0.f, 0.f, 0.f, 0.f, 0.f, 0.f};
    if (grow < M) {
      const float* ap = A + (size_t)grow * 128 + c * 8;
      *(float4*)&v[0] = *(const float4*)(ap);
      *(float4*)&v[4] = *(const float4*)(ap + 4);
      unsigned long long m0 = mask[2 * (size_t)grow];
      unsigned long long m1 = mask[2 * (size_t)grow + 1];
      int shift = c * 4;                         // (c*8)/2
      unsigned e = (unsigned)(m0 >> shift) & 0xFu;
      unsigned o = (unsigned)(m1 >> shift) & 0xFu;
      bn_mask8(v, scsh, c * 8, e, o);
    }
    *(float4*)&As[r][c * 8] = *(float4*)&v[0];
    *(float4*)&As[r][c * 8 + 4] = *(float4*)&v[4];
  }
  __syncthreads();
  float accl = 0.f, accr = 0.f;
#pragma unroll 4
  for (int k = 0; k < 128; ++k) {
    float a = As[r][k];                          // broadcast across 16 lanes
    accl += a * Wls[k][c];
    accr += a * Wrs[k][c];
  }
  int grow = row0 + r;
  if (grow < M) {
    Cl[(size_t)grow * 16 + c] = (unsigned short)f2bf(accl);
    Cr[(size_t)grow * 16 + c] = accr + br[c];
  }
}

// ---------------------------------------------------------------------------
// Z[n] (fp32) += agg(Yfp8)[n] / max(deg,1): one wave per node; the wave's
// two 32-lane halves process two edges per instruction; lane covers 4 fp8
// cols (uint load = whole 128 B row per half). fp8 rows = 2 lines/edge
// (R10 win). HW pk decode fp8→f32. Cross-half combine via __shfl; lanes
// 0..31 do the float4 Z update. Mask ballot stream = bit-identical dropout.
// ---------------------------------------------------------------------------
__global__ __launch_bounds__(THREADS) void aggregate128_fp8(
    const unsigned char* __restrict__ Y, float* __restrict__ Z,
    const int* __restrict__ colbuf, const int* __restrict__ start,
    const int* __restrict__ deg, unsigned long long* __restrict__ mask,
    unsigned mk0, unsigned mk1, int nnodes) {
  int w = (blockIdx.x * THREADS + threadIdx.x) >> 6;  // node = global wave id
  int lane = threadIdx.x & 63;
  if (w >= nnodes) return;
  // dropout mask bits for this node's row (index-only; overlaps the gathers)
  unsigned a0, a1, b0, b1;
  unsigned ib = (unsigned)w * 128u + (unsigned)(lane << 1);
  tf2x32(mk0, mk1, 0u, ib, &a0, &a1);
  tf2x32(mk0, mk1, 0u, ib + 1u, &b0, &b1);
  bool kp0 = ((a0 ^ a1) >> 31) == 0u;
  bool kp1 = ((b0 ^ b1) >> 31) == 0u;

  int half = lane >> 5;         // 0: even edge of pair, 1: odd edge
  int l32 = lane & 31;
  const int* cb = colbuf + start[w];
  int dg = deg[w];
  const unsigned char* yp = Y + (l32 << 2);      // 4 fp8 cols per lane
  float a0f = 0.f, a1f = 0.f, a2f = 0.f, a3f = 0.f;
  int i = 0;
#define ACC(u) { \
    f32x2 lo = __builtin_amdgcn_cvt_pk_f32_fp8((int)(u), false); \
    f32x2 hi = __builtin_amdgcn_cvt_pk_f32_fp8((int)(u), true);  \
    a0f += lo.x; a1f += lo.y; a2f += hi.x; a3f += hi.y; }
  for (; i + 8 <= dg; i += 8) {                  // 8 edges = 4 uint loads/lane
    int e0 = cb[i + half], e1 = cb[i + 2 + half];
    int e2 = cb[i + 4 + half], e3 = cb[i + 6 + half];
    unsigned u0 = *(const unsigned*)(yp + (size_t)e0 * 128);
    unsigned u1 = *(const unsigned*)(yp + (size_t)e1 * 128);
    unsigned u2 = *(const unsigned*)(yp + (size_t)e2 * 128);
    unsigned u3 = *(const unsigned*)(yp + (size_t)e3 * 128);
    ACC(u0) ACC(u1) ACC(u2) ACC(u3)
  }
  for (; i + 2 <= dg; i += 2) {
    int e0 = cb[i + half];
    unsigned u0 = *(const unsigned*)(yp + (size_t)e0 * 128);
    ACC(u0)
  }
  if (i < dg) {                                  // odd tail: half 0 only
    int e0 = cb[i];
    unsigned u0 = *(const unsigned*)(yp + (size_t)e0 * 128);
    if (half == 0) { ACC(u0) }
  }
#undef ACC
  // combine halves: lanes 0..31 += lanes 32..63 (same cols)
  a0f += __shfl(a0f, lane + 32);
  a1f += __shfl(a1f, lane + 32);
  a2f += __shfl(a2f, lane + 32);
  a3f += __shfl(a3f, lane + 32);

  unsigned long long bm0 = __ballot(kp0);
  unsigned long long bm1 = __ballot(kp1);
  if (lane == 0) {
    mask[2 * (size_t)w] = bm0;
    mask[2 * (size_t)w + 1] = bm1;
  }
  if (half == 0) {
    float sc = 1.0f / fmaxf((float)dg, 1.0f);
    float* zp = Z + (size_t)w * 128 + (l32 << 2);
    float4 z = *(const float4*)zp;
    z.x += a0f * sc;
    z.y += a1f * sc;
    z.z += a2f * sc;
    z.w += a3f * sc;
    *(float4*)zp = z;
  }
}

// Out[n] += agg(Y16bf16)[n] / max(deg,1): 8 threads/node, ×8 edge unroll.
__global__ __launch_bounds__(THREADS) void aggregate16_bf16(
    const unsigned short* __restrict__ Y, float* __restrict__ Out,
    const int* __restrict__ colbuf, const int* __restrict__ start,
    const int* __restrict__ deg, int nnodes) {
  int gid = blockIdx.x * THREADS + threadIdx.x;
  int n = gid >> 3;
  int cp = gid & 7;             // col pair: cols 2cp, 2cp+1
  if (n >= nnodes) return;
  const int* cb = colbuf + start[n];
  int dg = deg[n];
  const unsigned short* yp = Y + (cp << 1);
  float ax = 0.f, ay = 0.f;
  int i = 0;
  for (; i + 8 <= dg; i += 8) {
    int e[8];
#pragma unroll
    for (int j = 0; j < 8; ++j) e[j] = cb[i + j];
    unsigned u[8];
#pragma unroll
    for (int j = 0; j < 8; ++j) u[j] = *(const unsigned*)(yp + (size_t)e[j] * 16);
#pragma unroll
    for (int j = 0; j < 8; ++j) {
      ax += __uint_as_float(u[j] << 16);
      ay += __uint_as_float(u[j] & 0xffff0000u);
    }
  }
  for (; i < dg; ++i) {
    unsigned u = *(const unsigned*)(yp + (size_t)cb[i] * 16);
    ax += __uint_as_float(u << 16);
    ay += __uint_as_float(u & 0xffff0000u);
  }
  float sc = 1.0f / fmaxf((float)dg, 1.0f);
  size_t off = (size_t)n * 16 + (cp << 1);
  float2 o = *(const float2*)(Out + off);
  o.x += ax * sc;
  o.y += ay * sc;
  *(float2*)(Out + off) = o;
}

// ---------------------------------------------------------------------------
// BN: column sums/sumsq over fp32 h-state, @1024 blocks (R11 grid fix);
// finalize to scale/shift in a tiny separate dispatch (keeps GEMM VGPR low).
// ---------------------------------------------------------------------------
__global__ __launch_bounds__(THREADS) void bn_stats(const float* __restrict__ H,
                                                    float* __restrict__ sums, int n) {
  int col = threadIdx.x & 127;
  int half = threadIdx.x >> 7;  // 0/1
  float s = 0.f, sq = 0.f;
  for (int r = blockIdx.x * 2 + half; r < n; r += gridDim.x * 2) {
    float v = H[(size_t)r * 128 + col];
    s += v;
    sq += v * v;
  }
  __shared__ float ls[THREADS], lq[THREADS];
  ls[threadIdx.x] = s;
  lq[threadIdx.x] = sq;
  __syncthreads();
  if (half == 0) {
    s += ls[col + 128];
    sq += lq[col + 128];
    atomicAdd(&sums[col], s);
    atomicAdd(&sums[128 + col], sq);
  }
}

__global__ void bn_finalize(const float* __restrict__ sums,
                            const float* __restrict__ g,
                            const float* __restrict__ be,
                            float* __restrict__ scsh, float n) {
  int c = threadIdx.x;  // 128 threads
  float mu = sums[c] / n;
  float var = sums[128 + c] / n - mu * mu;
  float inv = rsqrtf(var + 1e-5f);
  float sc = g[c] * inv;
  scsh[c] = sc;
  scsh[128 + c] = be[c] - mu * sc;
}

// ---------------------------------------------------------------------------
// Launch: ONE memset; pack weights; CSR (plain-load fill @2048); per layer:
// fused MFMA dual GEMM (prev BN via scsh + precomputed mask; Cl fp8, Cr/h
// fp32), fp8 gather-agg (+ mask gen), bn_stats @1024, bn_finalize.
// Layer-3: fused dual 16-wide GEMM (bf16 Cl) + agg16.
// This build = union of best-measured components (R11 numerics + R12 fill).
// ---------------------------------------------------------------------------
extern "C" void kernel_launch(void* const* d_in, const int* in_sizes, int n_in,
                              void* d_out, int out_size, void* d_ws, size_t ws_size,
                              hipStream_t stream) {
  const float* x   = (const float*)d_in[0];
  const int* eidx  = (const int*)d_in[1];
  const float* W1l = (const float*)d_in[2];
  const float* W1r = (const float*)d_in[3];
  const float* b1  = (const float*)d_in[4];
  const float* g1  = (const float*)d_in[5];
  const float* be1 = (const float*)d_in[6];
  const float* W2l = (const float*)d_in[7];
  const float* W2r = (const float*)d_in[8];
  const float* b2  = (const float*)d_in[9];
  const float* g2  = (const float*)d_in[10];
  const float* be2 = (const float*)d_in[11];
  const float* W3l = (const float*)d_in[12];
  const float* W3r = (const float*)d_in[13];
  const float* b3  = (const float*)d_in[14];
  float* out = (float*)d_out;

  const int N = in_sizes[0] / 128;
  const int E = in_sizes[1] / 2;
  const int* esrc = eidx;
  const int* edst = eidx + E;

  size_t N128 = (size_t)N * 128;
  // Cleared region first (one memset): sums1(256) sums2(256) ideg(N) ifill(N)
  float* sums1 = (float*)d_ws;
  float* sums2 = sums1 + 256;
  int* ideg    = (int*)(sums2 + 256);
  int* ifill   = ideg + N;
  // Uncleared:
  int* istart  = ifill + N;
  int* iblksum = istart + N;                  // 512
  int* iblkbase = iblksum + 512;              // 512
  float* scsh1 = (float*)(iblkbase + 512);    // 256
  float* scsh2 = scsh1 + 256;                 // 256
  uint4* wp1 = (uint4*)(scsh2 + 256);         // 4096 uint4 each = 64 KB
  uint4* wp2 = wp1 + 4096;
  unsigned long long* mask1 = (unsigned long long*)(wp2 + 4096);  // N×2 u64
  unsigned long long* mask2 = mask1 + 2 * (size_t)N;
  int* icol  = (int*)(mask2 + 2 * (size_t)N);
  float* buf0 = (float*)(icol + E);           // fp8/bf16 N×128 lives here
  float* buf1 = buf0 + N128;                  // fp32 h-state N×128
  unsigned char* buf0b = (unsigned char*)buf0;   // fp8 view (layers 1-2)
  unsigned short* buf0h = (unsigned short*)buf0; // bf16 view (layer 3)

  // dropout keys: k1,k2 = split(key(42)) under partitionable threefry
  unsigned k1a, k1b, k2a, k2b;
  tf2x32(0u, 42u, 0u, 0u, &k1a, &k1b);
  tf2x32(0u, 42u, 0u, 1u, &k2a, &k2b);

  hipMemsetAsync(sums1, 0, (512 + 2 * (size_t)N) * 4, stream);

  pack_weights<<<16, THREADS, 0, stream>>>(W1l, W1r, wp1);
  pack_weights<<<16, THREADS, 0, stream>>>(W2l, W2r, wp2);

  int gE = (E + THREADS - 1) / THREADS;
  int gN = (N + THREADS - 1) / THREADS;      // == #scan blocks, must be <=512
  compute_deg<<<gE, THREADS, 0, stream>>>(edst, ideg, E);
  scan1_local<<<gN, THREADS, 0, stream>>>(ideg, istart, iblksum, N);
  scan2_blocks<<<1, 512, 0, stream>>>(iblksum, iblkbase, gN);
  scan3_add<<<gN, THREADS, 0, stream>>>(istart, iblkbase, N);
  int rngw = (N + 7) / 8;
  fill_csr_xcd<<<2048, THREADS, 0, stream>>>(esrc, edst, istart, ifill, icol, E, rngw);

  int gM64 = (N + 63) / 64;
  int gW = (N + 3) / 4;                 // aggregate128: 4 waves/block
  int gA16 = (N * 8 + THREADS - 1) / THREADS;
  float nf = (float)N;

  // ---- Layer 1 ----
  gemm_dual_mfma<0><<<gM64, THREADS, 0, stream>>>(x, wp1, b1, nullptr, nullptr,
                                                  buf0b, buf1, N);
  aggregate128_fp8<<<gW, THREADS, 0, stream>>>(buf0b, buf1, icol, istart, ideg,
                                               mask1, k1a, k1b, N);
  bn_stats<<<1024, THREADS, 0, stream>>>(buf1, sums1, N);
  bn_finalize<<<1, 128, 0, stream>>>(sums1, g1, be1, scsh1, nf);

  // ---- Layer 2 (BN1+ReLU+drop1 via scsh1+mask1; Cr in-place on buf1) ----
  gemm_dual_mfma<1><<<gM64, THREADS, 0, stream>>>(buf1, wp2, b2, scsh1, mask1,
                                                  buf0b, buf1, N);
  aggregate128_fp8<<<gW, THREADS, 0, stream>>>(buf0b, buf1, icol, istart, ideg,
                                               mask2, k2a, k2b, N);
  bn_stats<<<1024, THREADS, 0, stream>>>(buf1, sums2, N);
  bn_finalize<<<1, 128, 0, stream>>>(sums2, g2, be2, scsh2, nf);

  // ---- Layer 3 (BN2+ReLU+drop2 via scsh2+mask2 in dual 16-wide GEMM) ----
  gemm16_dual<<<(N + 15) / 16, THREADS, 0, stream>>>(buf1, W3l, W3r, b3, scsh2,
                                                     mask2, buf0h, out, N);
  aggregate16_bf16<<<gA16, THREADS, 0, stream>>>(buf0h, out, icol, istart, ideg, N);
}